// Round 6
// baseline (305.615 us; speedup 1.0000x reference)
//
#include <hip/hip_runtime.h>
#include <cstdint>

#define NP   4096      // patches
#define DD   768       // embed dim
#define HD   64
#define WD   64
#define KTOP 100
#define BIGL 4097      // N+1
#define NBLK 256       // k_tail grid

typedef short bf16x8 __attribute__((ext_vector_type(8)));
typedef float f32x4  __attribute__((ext_vector_type(4)));

__device__ __forceinline__ void gload_lds16(const void* g, void* l) {
    __builtin_amdgcn_global_load_lds(
        (const __attribute__((address_space(1))) unsigned int*)(uintptr_t)g,
        (__attribute__((address_space(3))) unsigned int*)(unsigned int)(uintptr_t)l,
        16, 0, 0);
}

__device__ __forceinline__ unsigned short f2bf_rne(float x) {
    unsigned b = __float_as_uint(x);
    unsigned r = b + 0x7FFFu + ((b >> 16) & 1u);
    return (unsigned short)(r >> 16);
}
__device__ __forceinline__ float bf2f(unsigned short h) {
    return __uint_as_float(((unsigned)h) << 16);
}

// ---------------- kernel 1: split A into bf16 hi+lo; zero counts & barriers ----------------
__global__ __launch_bounds__(256) void k_split(const float* __restrict__ A,
                                               unsigned short* __restrict__ hi,
                                               unsigned short* __restrict__ lo,
                                               int* __restrict__ counts,
                                               int* __restrict__ bar) {
    if (blockIdx.x < 16) counts[blockIdx.x * 256 + threadIdx.x] = 0;
    if (blockIdx.x == 16 && threadIdx.x < 16) bar[threadIdx.x] = 0;
    int idx = blockIdx.x * 256 + threadIdx.x;       // float4 index
    float4 v = ((const float4*)A)[idx];
    unsigned short h0 = f2bf_rne(v.x), h1 = f2bf_rne(v.y),
                   h2 = f2bf_rne(v.z), h3 = f2bf_rne(v.w);
    unsigned short l0 = f2bf_rne(v.x - bf2f(h0)), l1 = f2bf_rne(v.y - bf2f(h1)),
                   l2 = f2bf_rne(v.z - bf2f(h2)), l3 = f2bf_rne(v.w - bf2f(h3));
    ((ushort4*)hi)[idx] = make_ushort4(h0, h1, h2, h3);
    ((ushort4*)lo)[idx] = make_ushort4(l0, l1, l2, l3);
}

// ---------------- kernel 2: split-bf16 MFMA GEMM, double-buffered BK=64 ----------------
// LDS rows: 64 bf16 = 128B = 8 chunks of 16B; XOR swizzle kc^(row&7) -> conflict-free.
__device__ __forceinline__ void stage_tile(const unsigned short* __restrict__ aS,
                                           const unsigned short* __restrict__ bS,
                                           int i0, int j0, int kbase, int tid,
                                           unsigned short* As, unsigned short* Bs) {
#pragma unroll
    for (int q = 0; q < 4; ++q) {
        int p = q * 256 + tid;               // 16B chunk id, 1024 per tile
        int row = p >> 3, kcp = p & 7;
        int kclog = kcp ^ (row & 7);
        gload_lds16(aS + (size_t)(i0 + row) * DD + kbase + kclog * 8, As + p * 8);
        gload_lds16(bS + (size_t)(j0 + row) * DD + kbase + kclog * 8, Bs + p * 8);
    }
}

__global__ __launch_bounds__(256) void k_gemm(const unsigned short* __restrict__ hi,
                                              const unsigned short* __restrict__ lo,
                                              int* __restrict__ counts) {
    __shared__ __align__(16) unsigned short As[2][128 * 64];   // 2 x 16 KB
    __shared__ __align__(16) unsigned short Bs[2][128 * 64];   // 2 x 16 KB
    __shared__ int colc[128];
    __shared__ int rowc[128];

    // XCD-locality supertile remap (XCD = blockIdx%8 round-robin):
    int t = ((blockIdx.x & 7) * 66) + (blockIdx.x >> 3);
    int SI = 0, SJ = 0, rem = t;
    for (;;) {
        int sz = (SI == SJ) ? 36 : 64;
        if (rem < sz) break;
        rem -= sz;
        if (++SJ == 4) { ++SI; SJ = SI; }
    }
    int li, lj;
    if (SI == SJ) {
        int r = 0;
        while (rem >= (8 - r)) { rem -= (8 - r); ++r; }
        li = r; lj = r + rem;
    } else { li = rem >> 3; lj = rem & 7; }
    int bi = SI * 8 + li, bj = SJ * 8 + lj;
    int i0 = bi * 128, j0 = bj * 128;

    int tid = threadIdx.x;
    int lane = tid & 63, w = tid >> 6;
    int wm = w & 1, wn = w >> 1;      // wave quadrant: rows wm*64, cols wn*64

    f32x4 acc[4][4];
#pragma unroll
    for (int ti = 0; ti < 4; ++ti)
#pragma unroll
        for (int tj = 0; tj < 4; ++tj) { acc[ti][tj][0] = 0.f; acc[ti][tj][1] = 0.f;
                                         acc[ti][tj][2] = 0.f; acc[ti][tj][3] = 0.f; }

    stage_tile(hi, hi, i0, j0, 0, tid, As[0], Bs[0]);   // prologue: it=0 -> buf0
    for (int it = 0; it < 36; ++it) {
        int cur = it & 1;
        __syncthreads();   // buf[cur] loads done; prev compute on buf[cur^1] done
        if (it + 1 < 36) {
            int seg = (it + 1) / 12;           // 0: hi.hi  1: lo.hi  2: hi.lo
            int kb = ((it + 1) % 12) * 64;
            const unsigned short* aS = (seg == 1) ? lo : hi;
            const unsigned short* bS = (seg == 2) ? lo : hi;
            stage_tile(aS, bS, i0, j0, kb, tid, As[cur ^ 1], Bs[cur ^ 1]);
        }
#pragma unroll
        for (int s = 0; s < 2; ++s) {
            bf16x8 af[4], bfr[4];
#pragma unroll
            for (int tt = 0; tt < 4; ++tt) {
                int arow = wm * 64 + tt * 16 + (lane & 15);
                int kc = s * 4 + (lane >> 4);
                int pa = arow * 8 + (kc ^ (arow & 7));
                af[tt] = *(const bf16x8*)&As[cur][pa * 8];
                int brow = wn * 64 + tt * 16 + (lane & 15);
                int pb = brow * 8 + (kc ^ (brow & 7));
                bfr[tt] = *(const bf16x8*)&Bs[cur][pb * 8];
            }
#pragma unroll
            for (int ti = 0; ti < 4; ++ti)
#pragma unroll
                for (int tj = 0; tj < 4; ++tj)
                    acc[ti][tj] = __builtin_amdgcn_mfma_f32_16x16x32_bf16(
                        af[ti], bfr[tj], acc[ti][tj], 0, 0, 0);
        }
    }

    if (tid < 128) { colc[tid] = 0; rowc[tid] = 0; }
    __syncthreads();

    int nl = lane & 15;     // col within 16x16 tile
    int rg = lane >> 4;     // row group (rows rg*4 + reg)
#pragma unroll
    for (int ti = 0; ti < 4; ++ti)
#pragma unroll
        for (int tj = 0; tj < 4; ++tj) {
            f32x4 a = acc[ti][tj];
            int ct = ((a[0] >= 0.f) ? 1 : 0) + ((a[1] >= 0.f) ? 1 : 0) +
                     ((a[2] >= 0.f) ? 1 : 0) + ((a[3] >= 0.f) ? 1 : 0);
            ct += __shfl_xor(ct, 16);
            ct += __shfl_xor(ct, 32);
            if (rg == 0) atomicAdd(&colc[wn * 64 + tj * 16 + nl], ct);
            if (bi != bj) {
#pragma unroll
                for (int g = 0; g < 4; ++g) {
                    int rv = (a[g] >= 0.f) ? 1 : 0;
                    rv += __shfl_xor(rv, 1);
                    rv += __shfl_xor(rv, 2);
                    rv += __shfl_xor(rv, 4);
                    rv += __shfl_xor(rv, 8);
                    if (nl == 0) atomicAdd(&rowc[wm * 64 + ti * 16 + rg * 4 + g], rv);
                }
            }
        }
    __syncthreads();
    if (tid < 128) {
        atomicAdd(&counts[j0 + tid], colc[tid]);
        if (bi != bj) atomicAdd(&counts[i0 + tid], rowc[tid]);
    }
}

// ---------------- fused tail ----------------
// Grid barrier: RMW arrival + LOAD-ONLY spin (no ownership bouncing).
__device__ __forceinline__ void grid_barrier(int* bar, int idx) {
    __syncthreads();
    if (threadIdx.x == 0) {
        __threadfence();   // release: flush this XCD's dirty lines
        __hip_atomic_fetch_add(&bar[idx], 1, __ATOMIC_ACQ_REL, __HIP_MEMORY_SCOPE_AGENT);
        while (__hip_atomic_load(&bar[idx], __ATOMIC_ACQUIRE,
                                 __HIP_MEMORY_SCOPE_AGENT) < NBLK)
            __builtin_amdgcn_s_sleep(2);
        __threadfence();   // acquire: invalidate stale lines before block reads
    }
    __syncthreads();
}

__device__ __forceinline__ int block_sum256(int v, int lane, int w, int* wred) {
#pragma unroll
    for (int o = 1; o < 64; o <<= 1) v += __shfl_xor(v, o);
    if (lane == 0) wred[w] = v;
    __syncthreads();
    int tt = wred[0] + wred[1] + wred[2] + wred[3];
    __syncthreads();
    return tt;
}
__device__ __forceinline__ int block_exscan256(int v, int lane, int w, int* wred,
                                               int* total) {
    int inc = v;
#pragma unroll
    for (int o = 1; o < 64; o <<= 1) { int u = __shfl_up(inc, o); if (lane >= o) inc += u; }
    if (lane == 63) wred[w] = inc;
    __syncthreads();
    int w0 = wred[0], w1 = wred[1], w2 = wred[2], w3 = wred[3];
    int wofs = (w > 0 ? w0 : 0) + (w > 1 ? w1 : 0) + (w > 2 ? w2 : 0);
    *total = w0 + w1 + w2 + w3;
    __syncthreads();
    return wofs + inc - v;   // exclusive
}

__global__ __launch_bounds__(256) void k_tail(const float* __restrict__ A,
                                              const int* __restrict__ counts,
                                              const int* __restrict__ attn_seed,
                                              float* __restrict__ simrow,
                                              float* __restrict__ subsim,
                                              int* __restrict__ bar,
                                              int* __restrict__ outp) {
    __shared__ float ss[128 * 128];   // 64 KB: av (stage D) / subsim (stage E)
    __shared__ int redA[256], redB[256];
    __shared__ int wred[4];
    __shared__ int act_s[128];
    __shared__ int alive[128];
    __shared__ int lab[128];
    __shared__ int yyv[128], xxv[128];
    __shared__ int chg;
    int tid = threadIdx.x, lane = tid & 63, w = tid >> 6;
    int blk = blockIdx.x;

    // ---- stage A: EVERY block redundantly: argmin(counts) -> blended seed ----
    int seed;
    {
        int bc = 0x7fffffff, bI = 0;
        for (int j = tid; j < NP; j += 256) {
            int c = counts[j];
            if (c < bc) { bc = c; bI = j; }
        }
        redA[tid] = bc; redB[tid] = bI;
        __syncthreads();
        for (int st = 128; st > 0; st >>= 1) {
            if (tid < st) {
                if (redA[tid + st] < redA[tid] ||
                    (redA[tid + st] == redA[tid] && redB[tid + st] < redB[tid])) {
                    redA[tid] = redA[tid + st];
                    redB[tid] = redB[tid + st];
                }
            }
            __syncthreads();
        }
        int flat = redB[0];
        int sr = flat / WD, sc = flat % WD;
        int vr = sr + attn_seed[0];
        int vc = sc + attn_seed[1];
        int rr, rc;
        if ((vr & 1) == 0) rr = vr >> 1;
        else { int m = vr >> 1; rr = (m & 1) ? m + 1 : m; }   // round-half-to-even
        if ((vc & 1) == 0) rc = vc >> 1;
        else { int m = vc >> 1; rc = (m & 1) ? m + 1 : m; }
        seed = rr * WD + rc;
        __syncthreads();
    }

    // ---- stage B: distributed simrow (16 entries/block) + outp zeroing ----
    {
        int jbase = blk * 16 + w * 4;
        for (int jj = 0; jj < 4; ++jj) {
            int j = jbase + jj;
            float sum = 0.f;
#pragma unroll
            for (int kk = 0; kk < 12; ++kk) {
                int k = lane + kk * 64;
                sum += A[(size_t)seed * DD + k] * A[(size_t)j * DD + k];
            }
#pragma unroll
            for (int o = 32; o > 0; o >>= 1) sum += __shfl_down(sum, o);
            if (lane == 0) simrow[j] = sum;
        }
        if (tid < 16) outp[blk * 16 + tid] = 0;
    }
    grid_barrier(bar, 0);

    // ---- stage C: EVERY block redundantly: top-K select + compact into LDS ----
    int M;
    {
        int base = tid * 16;
        unsigned key[16];
#pragma unroll
        for (int n = 0; n < 16; ++n) {
            unsigned b = __float_as_uint(simrow[base + n]);
            key[n] = (b & 0x80000000u) ? ~b : (b | 0x80000000u);   // monotone encode
        }
        unsigned prefix = 0;
        for (int bit = 31; bit >= 0; --bit) {
            unsigned cand = prefix | (1u << bit);
            int c = 0;
#pragma unroll
            for (int n = 0; n < 16; ++n) c += (key[n] >= cand) ? 1 : 0;
            int tot = block_sum256(c, lane, w, wred);
            if (tot >= KTOP) prefix = cand;
        }
        unsigned KT = prefix;   // Kth-largest key
        int cgt = 0, ceq = 0;
#pragma unroll
        for (int n = 0; n < 16; ++n) {
            cgt += (key[n] > KT) ? 1 : 0;
            ceq += (key[n] == KT) ? 1 : 0;
        }
        int totgt = block_sum256(cgt, lane, w, wred);
        int slots = KTOP - totgt;   // #(==KT) kept, in index order
        int dummy;
        int eqrun = block_exscan256(ceq, lane, w, wred, &dummy);
        int flag[16]; int cf = 0;
#pragma unroll
        for (int n = 0; n < 16; ++n) {
            int j = base + n;
            unsigned k = key[n];
            int topk = (k > KT) || (k == KT && eqrun < slots);
            if (k == KT) ++eqrun;
            int f = (topk && (k >= 0x80000000u || j == seed)) ? 1 : 0;   // sim>=0 or seed
            flag[n] = f; cf += f;
        }
        int off = block_exscan256(cf, lane, w, wred, &M);
#pragma unroll
        for (int n = 0; n < 16; ++n)
            if (flag[n]) act_s[off++] = base + n;
        __syncthreads();
    }

    // ---- stage D: blocks 0..M-1: subsim row blk -> global ----
    if (blk < M) {
        int ip = act_s[blk];
        for (int k = tid; k < DD; k += 256) ss[k] = A[(size_t)ip * DD + k];
        __syncthreads();
        for (int q = w; q < M; q += 4) {
            int iq = act_s[q];
            float sum = 0.f;
#pragma unroll
            for (int kk = 0; kk < 12; ++kk) {
                int k = lane + kk * 64;
                sum += ss[k] * A[(size_t)iq * DD + k];
            }
#pragma unroll
            for (int o = 32; o > 0; o >>= 1) sum += __shfl_down(sum, o);
            if (lane == 0) subsim[blk * 128 + q] = sum;
        }
    }
    grid_barrier(bar, 1);

    // ---- stage E: block 0: expansion scan + CC over alive nodes ----
    if (blk != 0) return;
    for (int idx = tid; idx < M * 128; idx += 256) ss[idx] = subsim[idx];
    if (tid < 128) alive[tid] = 0;
    __syncthreads();

    if (tid < 64) {
        float al = (lane < M) ? 1.f : 0.f;
        float ah = (lane + 64 < M) ? 1.f : 0.f;
        for (int p = 0; p < M; p++) {
            float part = 0.f;
            if (lane < M)      part += ss[p * 128 + lane] * al;
            if (lane + 64 < M) part += ss[p * 128 + lane + 64] * ah;
#pragma unroll
            for (int o = 1; o < 64; o <<= 1) part += __shfl_xor(part, o);
            if (!(part > 0.f)) {
                if (lane == p)      al = 0.f;
                if (lane + 64 == p) ah = 0.f;
            }
        }
        alive[lane] = (lane < M && al != 0.f) ? 1 : 0;
        alive[lane + 64] = (lane + 64 < M && ah != 0.f) ? 1 : 0;
    }
    __syncthreads();

    if (tid < 128) {
        int a = (tid < M) ? alive[tid] : 0;
        int id = a ? act_s[tid] : 0;
        yyv[tid] = a ? (id >> 6) : -1000;
        xxv[tid] = a ? (id & 63) : -1000;
        lab[tid] = a ? (id + 1) : BIGL;
    }
    __syncthreads();
    while (true) {
        if (tid == 0) chg = 0;
        __syncthreads();
        int local = 0;
        if (tid < M && alive[tid]) {
            int m = lab[tid];
            int y = yyv[tid], x = xxv[tid];
            for (int q = 0; q < M; q++) {
                int dy = yyv[q] - y;
                if (dy < -1 || dy > 1) continue;
                int dx = xxv[q] - x;
                if (dx < -1 || dx > 1) continue;
                int u = lab[q];
                if (u < m) m = u;
            }
            if (m < lab[tid]) { lab[tid] = m; local = 1; }
        }
        if (local) chg = 1;
        __syncthreads();
        if (chg == 0) break;
        __syncthreads();
    }
    if (tid < M && alive[tid]) outp[act_s[tid]] = lab[tid];
}

extern "C" void kernel_launch(void* const* d_in, const int* in_sizes, int n_in,
                              void* d_out, int out_size, void* d_ws, size_t ws_size,
                              hipStream_t stream) {
    const float* A = (const float*)d_in[0];       // out: (4096, 768) fp32
    const int* attn = (const int*)d_in[1];        // attn_seed: (2,) int32
    int* outp = (int*)d_out;                      // labels: (64,64) int32

    char* ws = (char*)d_ws;
    int*            counts = (int*)(ws);                    // 16 KB
    float*          simrow = (float*)(ws + 16384);          // 16 KB
    int*            bar    = (int*)(ws + 33344);            // 16 ints (64B-aligned)
    float*          subsim = (float*)(ws + 33792);          // 64 KB
    unsigned short* hi     = (unsigned short*)(ws + 1048576);           // 6.29 MB
    unsigned short* lo     = (unsigned short*)(ws + 1048576 + 6291456); // 6.29 MB

    k_split <<<3072, 256, 0, stream>>>(A, hi, lo, counts, bar);
    k_gemm  <<<528,  256, 0, stream>>>(hi, lo, counts);
    k_tail  <<<NBLK, 256, 0, stream>>>(A, counts, attn, simrow, subsim, bar, outp);
}

// Round 7
// 251.261 us; speedup vs baseline: 1.2163x; 1.2163x over previous
//
#include <hip/hip_runtime.h>
#include <cstdint>

#define NP   4096      // patches
#define DD   768       // embed dim
#define HD   64
#define WD   64
#define KTOP 100
#define BIGL 4097      // N+1
#define NBLK 128       // k_tail grid

typedef short bf16x8 __attribute__((ext_vector_type(8)));
typedef float f32x4  __attribute__((ext_vector_type(4)));

__device__ __forceinline__ void gload_lds16(const void* g, void* l) {
    __builtin_amdgcn_global_load_lds(
        (const __attribute__((address_space(1))) unsigned int*)(uintptr_t)g,
        (__attribute__((address_space(3))) unsigned int*)(unsigned int)(uintptr_t)l,
        16, 0, 0);
}

__device__ __forceinline__ unsigned short f2bf_rne(float x) {
    unsigned b = __float_as_uint(x);
    unsigned r = b + 0x7FFFu + ((b >> 16) & 1u);
    return (unsigned short)(r >> 16);
}
__device__ __forceinline__ float bf2f(unsigned short h) {
    return __uint_as_float(((unsigned)h) << 16);
}

// ---------------- kernel 1: split A into bf16 hi+lo; zero counts & barriers ----------------
__global__ __launch_bounds__(256) void k_split(const float* __restrict__ A,
                                               unsigned short* __restrict__ hi,
                                               unsigned short* __restrict__ lo,
                                               int* __restrict__ counts,
                                               int* __restrict__ bar) {
    if (blockIdx.x < 16) counts[blockIdx.x * 256 + threadIdx.x] = 0;
    if (blockIdx.x == 16 && threadIdx.x < 16) bar[threadIdx.x] = 0;
    int idx = blockIdx.x * 256 + threadIdx.x;       // float4 index
    float4 v = ((const float4*)A)[idx];
    unsigned short h0 = f2bf_rne(v.x), h1 = f2bf_rne(v.y),
                   h2 = f2bf_rne(v.z), h3 = f2bf_rne(v.w);
    unsigned short l0 = f2bf_rne(v.x - bf2f(h0)), l1 = f2bf_rne(v.y - bf2f(h1)),
                   l2 = f2bf_rne(v.z - bf2f(h2)), l3 = f2bf_rne(v.w - bf2f(h3));
    ((ushort4*)hi)[idx] = make_ushort4(h0, h1, h2, h3);
    ((ushort4*)lo)[idx] = make_ushort4(l0, l1, l2, l3);
}

// ---------------- kernel 2: split-bf16 MFMA GEMM, 4-tile K=32 groups, dbuf ----------------
// Group = [hiA | loA | hiB | loB], each 128 rows x 32 bf16 (64B row = 4 chunks of 16B).
// Chunk bijection phys = (row*4 + (kc^(row&3))) ^ (row&4):
//   - staging stays contiguous-per-wave (global_load_lds constraint)
//   - frag ds_read_b128: 8 consecutive rows cover all 8 bank-quads -> 2-way only (free)
__device__ __forceinline__ void stage_group(const unsigned short* __restrict__ hi,
                                            const unsigned short* __restrict__ lo,
                                            int i0, int j0, int kbase, int tid,
                                            unsigned short* G) {
    const unsigned short* srcs[4] = {
        hi + (size_t)i0 * DD + kbase, lo + (size_t)i0 * DD + kbase,
        hi + (size_t)j0 * DD + kbase, lo + (size_t)j0 * DD + kbase };
#pragma unroll
    for (int q = 0; q < 8; ++q) {
        const int tile = q >> 1;                 // compile-time per unrolled q
        int pp = (q & 1) * 256 + tid;            // phys chunk 0..511 within tile
        int u = pp >> 2;
        int row = u ^ ((u >> 2) & 1);            // inverse of the bijection
        int kc = (pp & 3) ^ (row & 3);
        gload_lds16(srcs[tile] + (size_t)row * DD + kc * 8,
                    G + (tile * 512 + pp) * 8);
    }
}

__global__ __launch_bounds__(256) void k_gemm(const unsigned short* __restrict__ hi,
                                              const unsigned short* __restrict__ lo,
                                              int* __restrict__ counts) {
    __shared__ __align__(16) unsigned short G[2][4 * 512 * 8];   // 2 x 32 KB
    __shared__ int colc[128];
    __shared__ int rowc[128];

    // XCD-locality supertile remap (XCD = blockIdx%8 round-robin):
    int t = ((blockIdx.x & 7) * 66) + (blockIdx.x >> 3);
    int SI = 0, SJ = 0, rem = t;
    for (;;) {
        int sz = (SI == SJ) ? 36 : 64;
        if (rem < sz) break;
        rem -= sz;
        if (++SJ == 4) { ++SI; SJ = SI; }
    }
    int li, lj;
    if (SI == SJ) {
        int r = 0;
        while (rem >= (8 - r)) { rem -= (8 - r); ++r; }
        li = r; lj = r + rem;
    } else { li = rem >> 3; lj = rem & 7; }
    int bi = SI * 8 + li, bj = SJ * 8 + lj;
    int i0 = bi * 128, j0 = bj * 128;

    int tid = threadIdx.x;
    int lane = tid & 63, w = tid >> 6;
    int wm = w & 1, wn = w >> 1;      // wave quadrant: rows wm*64, cols wn*64

    f32x4 acc[4][4];
#pragma unroll
    for (int ti = 0; ti < 4; ++ti)
#pragma unroll
        for (int tj = 0; tj < 4; ++tj) { acc[ti][tj][0] = 0.f; acc[ti][tj][1] = 0.f;
                                         acc[ti][tj][2] = 0.f; acc[ti][tj][3] = 0.f; }

    // precompute frag phys-chunk offsets (K-slice-independent)
    int kcf = lane >> 4;              // 0..3
    int pa[4], pb[4];
#pragma unroll
    for (int tt = 0; tt < 4; ++tt) {
        int arow = wm * 64 + tt * 16 + (lane & 15);
        pa[tt] = ((arow * 4 + (kcf ^ (arow & 3))) ^ (arow & 4));
        int brow = wn * 64 + tt * 16 + (lane & 15);
        pb[tt] = ((brow * 4 + (kcf ^ (brow & 3))) ^ (brow & 4));
    }

    stage_group(hi, lo, i0, j0, 0, tid, G[0]);   // prologue
    for (int it = 0; it < 24; ++it) {
        int cur = it & 1;
        __syncthreads();   // buf[cur] loads done; prev compute on buf[cur^1] done
        if (it + 1 < 24)
            stage_group(hi, lo, i0, j0, (it + 1) * 32, tid, G[cur ^ 1]);
        bf16x8 ahi[4], alo[4], bhi[4], blo[4];
#pragma unroll
        for (int tt = 0; tt < 4; ++tt) {
            ahi[tt] = *(const bf16x8*)&G[cur][(0 * 512 + pa[tt]) * 8];
            alo[tt] = *(const bf16x8*)&G[cur][(1 * 512 + pa[tt]) * 8];
            bhi[tt] = *(const bf16x8*)&G[cur][(2 * 512 + pb[tt]) * 8];
            blo[tt] = *(const bf16x8*)&G[cur][(3 * 512 + pb[tt]) * 8];
        }
#pragma unroll
        for (int ti = 0; ti < 4; ++ti)
#pragma unroll
            for (int tj = 0; tj < 4; ++tj) {
                acc[ti][tj] = __builtin_amdgcn_mfma_f32_16x16x32_bf16(
                    ahi[ti], bhi[tj], acc[ti][tj], 0, 0, 0);
                acc[ti][tj] = __builtin_amdgcn_mfma_f32_16x16x32_bf16(
                    alo[ti], bhi[tj], acc[ti][tj], 0, 0, 0);
                acc[ti][tj] = __builtin_amdgcn_mfma_f32_16x16x32_bf16(
                    ahi[ti], blo[tj], acc[ti][tj], 0, 0, 0);
            }
    }

    if (tid < 128) { colc[tid] = 0; rowc[tid] = 0; }
    __syncthreads();

    int nl = lane & 15;     // col within 16x16 tile
    int rg = lane >> 4;     // row group (rows rg*4 + reg)
#pragma unroll
    for (int ti = 0; ti < 4; ++ti)
#pragma unroll
        for (int tj = 0; tj < 4; ++tj) {
            f32x4 a = acc[ti][tj];
            int ct = ((a[0] >= 0.f) ? 1 : 0) + ((a[1] >= 0.f) ? 1 : 0) +
                     ((a[2] >= 0.f) ? 1 : 0) + ((a[3] >= 0.f) ? 1 : 0);
            ct += __shfl_xor(ct, 16);
            ct += __shfl_xor(ct, 32);
            if (rg == 0) atomicAdd(&colc[wn * 64 + tj * 16 + nl], ct);
            if (bi != bj) {
#pragma unroll
                for (int g = 0; g < 4; ++g) {
                    int rv = (a[g] >= 0.f) ? 1 : 0;
                    rv += __shfl_xor(rv, 1);
                    rv += __shfl_xor(rv, 2);
                    rv += __shfl_xor(rv, 4);
                    rv += __shfl_xor(rv, 8);
                    if (nl == 0) atomicAdd(&rowc[wm * 64 + ti * 16 + rg * 4 + g], rv);
                }
            }
        }
    __syncthreads();
    if (tid < 128) {
        atomicAdd(&counts[j0 + tid], colc[tid]);
        if (bi != bj) atomicAdd(&counts[i0 + tid], rowc[tid]);
    }
}

// ---------------- fused tail ----------------
// Grid barrier: release-RMW arrival, RELAXED load spin (no per-poll invalidate),
// long sleep between polls, single device fence after exit.
__device__ __forceinline__ void grid_barrier(int* bar, int idx) {
    __syncthreads();
    if (threadIdx.x == 0) {
        __threadfence();   // release: order prior stores at device scope
        __hip_atomic_fetch_add(&bar[idx], 1, __ATOMIC_RELEASE, __HIP_MEMORY_SCOPE_AGENT);
        while (__hip_atomic_load(&bar[idx], __ATOMIC_RELAXED,
                                 __HIP_MEMORY_SCOPE_AGENT) < NBLK)
            __builtin_amdgcn_s_sleep(32);   // ~2048 cyc between polls
        __threadfence();   // acquire: discard stale cached lines
    }
    __syncthreads();
}

__device__ __forceinline__ int block_sum256(int v, int lane, int w, int* wred) {
#pragma unroll
    for (int o = 1; o < 64; o <<= 1) v += __shfl_xor(v, o);
    if (lane == 0) wred[w] = v;
    __syncthreads();
    int tt = wred[0] + wred[1] + wred[2] + wred[3];
    __syncthreads();
    return tt;
}
__device__ __forceinline__ int block_exscan256(int v, int lane, int w, int* wred,
                                               int* total) {
    int inc = v;
#pragma unroll
    for (int o = 1; o < 64; o <<= 1) { int u = __shfl_up(inc, o); if (lane >= o) inc += u; }
    if (lane == 63) wred[w] = inc;
    __syncthreads();
    int w0 = wred[0], w1 = wred[1], w2 = wred[2], w3 = wred[3];
    int wofs = (w > 0 ? w0 : 0) + (w > 1 ? w1 : 0) + (w > 2 ? w2 : 0);
    *total = w0 + w1 + w2 + w3;
    __syncthreads();
    return wofs + inc - v;   // exclusive
}

__global__ __launch_bounds__(256) void k_tail(const float* __restrict__ A,
                                              const int* __restrict__ counts,
                                              const int* __restrict__ attn_seed,
                                              float* __restrict__ simrow,
                                              float* __restrict__ subsim,
                                              int* __restrict__ bar,
                                              int* __restrict__ outp) {
    __shared__ float ss[128 * 128];   // 64 KB: av (stage D) / subsim (stage E)
    __shared__ int redA[256], redB[256];
    __shared__ int wred[4];
    __shared__ int act_s[128];
    __shared__ int alive[128];
    __shared__ int lab[128];
    __shared__ int yyv[128], xxv[128];
    __shared__ int chg;
    int tid = threadIdx.x, lane = tid & 63, w = tid >> 6;
    int blk = blockIdx.x;

    // ---- stage A: EVERY block redundantly: argmin(counts) -> blended seed ----
    int seed;
    {
        int bc = 0x7fffffff, bI = 0;
        for (int j = tid; j < NP; j += 256) {
            int c = counts[j];
            if (c < bc) { bc = c; bI = j; }
        }
        redA[tid] = bc; redB[tid] = bI;
        __syncthreads();
        for (int st = 128; st > 0; st >>= 1) {
            if (tid < st) {
                if (redA[tid + st] < redA[tid] ||
                    (redA[tid + st] == redA[tid] && redB[tid + st] < redB[tid])) {
                    redA[tid] = redA[tid + st];
                    redB[tid] = redB[tid + st];
                }
            }
            __syncthreads();
        }
        int flat = redB[0];
        int sr = flat / WD, sc = flat % WD;
        int vr = sr + attn_seed[0];
        int vc = sc + attn_seed[1];
        int rr, rc;
        if ((vr & 1) == 0) rr = vr >> 1;
        else { int m = vr >> 1; rr = (m & 1) ? m + 1 : m; }   // round-half-to-even
        if ((vc & 1) == 0) rc = vc >> 1;
        else { int m = vc >> 1; rc = (m & 1) ? m + 1 : m; }
        seed = rr * WD + rc;
        __syncthreads();
    }

    // ---- stage B: distributed simrow (32 entries/block) + outp zeroing ----
    {
        float sv[12];
#pragma unroll
        for (int kk = 0; kk < 12; ++kk) sv[kk] = A[(size_t)seed * DD + lane + kk * 64];
        int jbase = blk * 32 + w * 8;
        for (int jj = 0; jj < 8; ++jj) {
            int j = jbase + jj;
            float sum = 0.f;
#pragma unroll
            for (int kk = 0; kk < 12; ++kk)
                sum += sv[kk] * A[(size_t)j * DD + lane + kk * 64];
#pragma unroll
            for (int o = 32; o > 0; o >>= 1) sum += __shfl_down(sum, o);
            if (lane == 0) simrow[j] = sum;
        }
        if (tid < 32) outp[blk * 32 + tid] = 0;
    }
    grid_barrier(bar, 0);

    // ---- stage C: EVERY block redundantly: top-K select + compact into LDS ----
    int M;
    {
        int base = tid * 16;
        unsigned key[16];
#pragma unroll
        for (int n = 0; n < 16; ++n) {
            unsigned b = __float_as_uint(simrow[base + n]);
            key[n] = (b & 0x80000000u) ? ~b : (b | 0x80000000u);   // monotone encode
        }
        unsigned prefix = 0;
        for (int bit = 31; bit >= 0; --bit) {
            unsigned cand = prefix | (1u << bit);
            int c = 0;
#pragma unroll
            for (int n = 0; n < 16; ++n) c += (key[n] >= cand) ? 1 : 0;
            int tot = block_sum256(c, lane, w, wred);
            if (tot >= KTOP) prefix = cand;
        }
        unsigned KT = prefix;   // Kth-largest key
        int cgt = 0, ceq = 0;
#pragma unroll
        for (int n = 0; n < 16; ++n) {
            cgt += (key[n] > KT) ? 1 : 0;
            ceq += (key[n] == KT) ? 1 : 0;
        }
        int totgt = block_sum256(cgt, lane, w, wred);
        int slots = KTOP - totgt;   // #(==KT) kept, in index order
        int dummy;
        int eqrun = block_exscan256(ceq, lane, w, wred, &dummy);
        int flag[16]; int cf = 0;
#pragma unroll
        for (int n = 0; n < 16; ++n) {
            int j = base + n;
            unsigned k = key[n];
            int topk = (k > KT) || (k == KT && eqrun < slots);
            if (k == KT) ++eqrun;
            int f = (topk && (k >= 0x80000000u || j == seed)) ? 1 : 0;   // sim>=0 or seed
            flag[n] = f; cf += f;
        }
        int off = block_exscan256(cf, lane, w, wred, &M);
#pragma unroll
        for (int n = 0; n < 16; ++n)
            if (flag[n]) act_s[off++] = base + n;
        __syncthreads();
    }

    // ---- stage D: blocks 0..M-1: subsim row blk -> global ----
    if (blk < M) {
        int ip = act_s[blk];
        for (int k = tid; k < DD; k += 256) ss[k] = A[(size_t)ip * DD + k];
        __syncthreads();
        for (int q = w; q < M; q += 4) {
            int iq = act_s[q];
            float sum = 0.f;
#pragma unroll
            for (int kk = 0; kk < 12; ++kk) {
                int k = lane + kk * 64;
                sum += ss[k] * A[(size_t)iq * DD + k];
            }
#pragma unroll
            for (int o = 32; o > 0; o >>= 1) sum += __shfl_down(sum, o);
            if (lane == 0) subsim[blk * 128 + q] = sum;
        }
    }
    grid_barrier(bar, 1);

    // ---- stage E: block 0: expansion scan + CC over alive nodes ----
    if (blk != 0) return;
    for (int idx = tid; idx < M * 128; idx += 256) ss[idx] = subsim[idx];
    if (tid < 128) alive[tid] = 0;
    __syncthreads();

    if (tid < 64) {
        float al = (lane < M) ? 1.f : 0.f;
        float ah = (lane + 64 < M) ? 1.f : 0.f;
        for (int p = 0; p < M; p++) {
            float part = 0.f;
            if (lane < M)      part += ss[p * 128 + lane] * al;
            if (lane + 64 < M) part += ss[p * 128 + lane + 64] * ah;
#pragma unroll
            for (int o = 1; o < 64; o <<= 1) part += __shfl_xor(part, o);
            if (!(part > 0.f)) {
                if (lane == p)      al = 0.f;
                if (lane + 64 == p) ah = 0.f;
            }
        }
        alive[lane] = (lane < M && al != 0.f) ? 1 : 0;
        alive[lane + 64] = (lane + 64 < M && ah != 0.f) ? 1 : 0;
    }
    __syncthreads();

    if (tid < 128) {
        int a = (tid < M) ? alive[tid] : 0;
        int id = a ? act_s[tid] : 0;
        yyv[tid] = a ? (id >> 6) : -1000;
        xxv[tid] = a ? (id & 63) : -1000;
        lab[tid] = a ? (id + 1) : BIGL;
    }
    __syncthreads();
    while (true) {
        if (tid == 0) chg = 0;
        __syncthreads();
        int local = 0;
        if (tid < M && alive[tid]) {
            int m = lab[tid];
            int y = yyv[tid], x = xxv[tid];
            for (int q = 0; q < M; q++) {
                int dy = yyv[q] - y;
                if (dy < -1 || dy > 1) continue;
                int dx = xxv[q] - x;
                if (dx < -1 || dx > 1) continue;
                int u = lab[q];
                if (u < m) m = u;
            }
            if (m < lab[tid]) { lab[tid] = m; local = 1; }
        }
        if (local) chg = 1;
        __syncthreads();
        if (chg == 0) break;
        __syncthreads();
    }
    if (tid < M && alive[tid]) outp[act_s[tid]] = lab[tid];
}

extern "C" void kernel_launch(void* const* d_in, const int* in_sizes, int n_in,
                              void* d_out, int out_size, void* d_ws, size_t ws_size,
                              hipStream_t stream) {
    const float* A = (const float*)d_in[0];       // out: (4096, 768) fp32
    const int* attn = (const int*)d_in[1];        // attn_seed: (2,) int32
    int* outp = (int*)d_out;                      // labels: (64,64) int32

    char* ws = (char*)d_ws;
    int*            counts = (int*)(ws);                    // 16 KB
    float*          simrow = (float*)(ws + 16384);          // 16 KB
    int*            bar    = (int*)(ws + 33344);            // 16 ints (64B-aligned)
    float*          subsim = (float*)(ws + 33792);          // 64 KB
    unsigned short* hi     = (unsigned short*)(ws + 1048576);           // 6.29 MB
    unsigned short* lo     = (unsigned short*)(ws + 1048576 + 6291456); // 6.29 MB

    k_split <<<3072, 256, 0, stream>>>(A, hi, lo, counts, bar);
    k_gemm  <<<528,  256, 0, stream>>>(hi, lo, counts);
    k_tail  <<<NBLK, 256, 0, stream>>>(A, counts, attn, simrow, subsim, bar, outp);
}

// Round 8
// 219.688 us; speedup vs baseline: 1.3911x; 1.1437x over previous
//
#include <hip/hip_runtime.h>
#include <cstdint>

#define NP   4096      // patches
#define DD   768       // embed dim
#define HD   64
#define WD   64
#define KTOP 100
#define BIGL 4097      // N+1
#define NBLK 128       // k_tail grid

typedef short bf16x8 __attribute__((ext_vector_type(8)));
typedef float f32x4  __attribute__((ext_vector_type(4)));

__device__ __forceinline__ void gload_lds16(const void* g, void* l) {
    __builtin_amdgcn_global_load_lds(
        (const __attribute__((address_space(1))) unsigned int*)(uintptr_t)g,
        (__attribute__((address_space(3))) unsigned int*)(unsigned int)(uintptr_t)l,
        16, 0, 0);
}

__device__ __forceinline__ unsigned short f2bf_rne(float x) {
    unsigned b = __float_as_uint(x);
    unsigned r = b + 0x7FFFu + ((b >> 16) & 1u);
    return (unsigned short)(r >> 16);
}
__device__ __forceinline__ float bf2f(unsigned short h) {
    return __uint_as_float(((unsigned)h) << 16);
}

// ---------------- kernel 1: split A into bf16 hi+lo; zero counts & barriers ----------------
__global__ __launch_bounds__(256) void k_split(const float* __restrict__ A,
                                               unsigned short* __restrict__ hi,
                                               unsigned short* __restrict__ lo,
                                               int* __restrict__ counts,
                                               int* __restrict__ bar) {
    if (blockIdx.x < 16) counts[blockIdx.x * 256 + threadIdx.x] = 0;
    if (blockIdx.x == 16 && threadIdx.x < 16) bar[threadIdx.x] = 0;
    int idx = blockIdx.x * 256 + threadIdx.x;       // float4 index
    float4 v = ((const float4*)A)[idx];
    unsigned short h0 = f2bf_rne(v.x), h1 = f2bf_rne(v.y),
                   h2 = f2bf_rne(v.z), h3 = f2bf_rne(v.w);
    unsigned short l0 = f2bf_rne(v.x - bf2f(h0)), l1 = f2bf_rne(v.y - bf2f(h1)),
                   l2 = f2bf_rne(v.z - bf2f(h2)), l3 = f2bf_rne(v.w - bf2f(h3));
    ((ushort4*)hi)[idx] = make_ushort4(h0, h1, h2, h3);
    ((ushort4*)lo)[idx] = make_ushort4(l0, l1, l2, l3);
}

// ---------------- kernel 2: split-bf16 MFMA GEMM, 4-tile K=32 groups, dbuf ----------------
__device__ __forceinline__ void stage_group(const unsigned short* __restrict__ hi,
                                            const unsigned short* __restrict__ lo,
                                            int i0, int j0, int kbase, int tid,
                                            unsigned short* G) {
    const unsigned short* srcs[4] = {
        hi + (size_t)i0 * DD + kbase, lo + (size_t)i0 * DD + kbase,
        hi + (size_t)j0 * DD + kbase, lo + (size_t)j0 * DD + kbase };
#pragma unroll
    for (int q = 0; q < 8; ++q) {
        const int tile = q >> 1;
        int pp = (q & 1) * 256 + tid;            // phys chunk 0..511 within tile
        int u = pp >> 2;
        int row = u ^ ((u >> 2) & 1);            // inverse of the bijection
        int kc = (pp & 3) ^ (row & 3);
        gload_lds16(srcs[tile] + (size_t)row * DD + kc * 8,
                    G + (tile * 512 + pp) * 8);
    }
}

__global__ __launch_bounds__(256) void k_gemm(const unsigned short* __restrict__ hi,
                                              const unsigned short* __restrict__ lo,
                                              int* __restrict__ counts) {
    __shared__ __align__(16) unsigned short G[2][4 * 512 * 8];   // 2 x 32 KB
    __shared__ int colc[128];
    __shared__ int rowc[128];

    // XCD-locality supertile remap (XCD = blockIdx%8 round-robin):
    int t = ((blockIdx.x & 7) * 66) + (blockIdx.x >> 3);
    int SI = 0, SJ = 0, rem = t;
    for (;;) {
        int sz = (SI == SJ) ? 36 : 64;
        if (rem < sz) break;
        rem -= sz;
        if (++SJ == 4) { ++SI; SJ = SI; }
    }
    int li, lj;
    if (SI == SJ) {
        int r = 0;
        while (rem >= (8 - r)) { rem -= (8 - r); ++r; }
        li = r; lj = r + rem;
    } else { li = rem >> 3; lj = rem & 7; }
    int bi = SI * 8 + li, bj = SJ * 8 + lj;
    int i0 = bi * 128, j0 = bj * 128;

    int tid = threadIdx.x;
    int lane = tid & 63, w = tid >> 6;
    int wm = w & 1, wn = w >> 1;

    f32x4 acc[4][4];
#pragma unroll
    for (int ti = 0; ti < 4; ++ti)
#pragma unroll
        for (int tj = 0; tj < 4; ++tj) { acc[ti][tj][0] = 0.f; acc[ti][tj][1] = 0.f;
                                         acc[ti][tj][2] = 0.f; acc[ti][tj][3] = 0.f; }

    int kcf = lane >> 4;
    int pa[4], pb[4];
#pragma unroll
    for (int tt = 0; tt < 4; ++tt) {
        int arow = wm * 64 + tt * 16 + (lane & 15);
        pa[tt] = ((arow * 4 + (kcf ^ (arow & 3))) ^ (arow & 4));
        int brow = wn * 64 + tt * 16 + (lane & 15);
        pb[tt] = ((brow * 4 + (kcf ^ (brow & 3))) ^ (brow & 4));
    }

    stage_group(hi, lo, i0, j0, 0, tid, G[0]);   // prologue
    for (int it = 0; it < 24; ++it) {
        int cur = it & 1;
        __syncthreads();
        if (it + 1 < 24)
            stage_group(hi, lo, i0, j0, (it + 1) * 32, tid, G[cur ^ 1]);
        bf16x8 ahi[4], alo[4], bhi[4], blo[4];
#pragma unroll
        for (int tt = 0; tt < 4; ++tt) {
            ahi[tt] = *(const bf16x8*)&G[cur][(0 * 512 + pa[tt]) * 8];
            alo[tt] = *(const bf16x8*)&G[cur][(1 * 512 + pa[tt]) * 8];
            bhi[tt] = *(const bf16x8*)&G[cur][(2 * 512 + pb[tt]) * 8];
            blo[tt] = *(const bf16x8*)&G[cur][(3 * 512 + pb[tt]) * 8];
        }
#pragma unroll
        for (int ti = 0; ti < 4; ++ti)
#pragma unroll
            for (int tj = 0; tj < 4; ++tj) {
                acc[ti][tj] = __builtin_amdgcn_mfma_f32_16x16x32_bf16(
                    ahi[ti], bhi[tj], acc[ti][tj], 0, 0, 0);
                acc[ti][tj] = __builtin_amdgcn_mfma_f32_16x16x32_bf16(
                    alo[ti], bhi[tj], acc[ti][tj], 0, 0, 0);
                acc[ti][tj] = __builtin_amdgcn_mfma_f32_16x16x32_bf16(
                    ahi[ti], blo[tj], acc[ti][tj], 0, 0, 0);
            }
    }

    if (tid < 128) { colc[tid] = 0; rowc[tid] = 0; }
    __syncthreads();

    int nl = lane & 15;
    int rg = lane >> 4;
#pragma unroll
    for (int ti = 0; ti < 4; ++ti)
#pragma unroll
        for (int tj = 0; tj < 4; ++tj) {
            f32x4 a = acc[ti][tj];
            int ct = ((a[0] >= 0.f) ? 1 : 0) + ((a[1] >= 0.f) ? 1 : 0) +
                     ((a[2] >= 0.f) ? 1 : 0) + ((a[3] >= 0.f) ? 1 : 0);
            ct += __shfl_xor(ct, 16);
            ct += __shfl_xor(ct, 32);
            if (rg == 0) atomicAdd(&colc[wn * 64 + tj * 16 + nl], ct);
            if (bi != bj) {
#pragma unroll
                for (int g = 0; g < 4; ++g) {
                    int rv = (a[g] >= 0.f) ? 1 : 0;
                    rv += __shfl_xor(rv, 1);
                    rv += __shfl_xor(rv, 2);
                    rv += __shfl_xor(rv, 4);
                    rv += __shfl_xor(rv, 8);
                    if (nl == 0) atomicAdd(&rowc[wm * 64 + ti * 16 + rg * 4 + g], rv);
                }
            }
        }
    __syncthreads();
    if (tid < 128) {
        atomicAdd(&counts[j0 + tid], colc[tid]);
        if (bi != bj) atomicAdd(&counts[i0 + tid], rowc[tid]);
    }
}

// ---------------- fused tail ----------------
__device__ __forceinline__ void grid_barrier(int* bar, int idx) {
    __syncthreads();
    if (threadIdx.x == 0) {
        __threadfence();
        __hip_atomic_fetch_add(&bar[idx], 1, __ATOMIC_RELEASE, __HIP_MEMORY_SCOPE_AGENT);
        while (__hip_atomic_load(&bar[idx], __ATOMIC_RELAXED,
                                 __HIP_MEMORY_SCOPE_AGENT) < NBLK)
            __builtin_amdgcn_s_sleep(32);
        __threadfence();
    }
    __syncthreads();
}

__device__ __forceinline__ int block_sum256(int v, int lane, int w, int* wred) {
#pragma unroll
    for (int o = 1; o < 64; o <<= 1) v += __shfl_xor(v, o);
    if (lane == 0) wred[w] = v;
    __syncthreads();
    int tt = wred[0] + wred[1] + wred[2] + wred[3];
    __syncthreads();
    return tt;
}
__device__ __forceinline__ int block_exscan256(int v, int lane, int w, int* wred,
                                               int* total) {
    int inc = v;
#pragma unroll
    for (int o = 1; o < 64; o <<= 1) { int u = __shfl_up(inc, o); if (lane >= o) inc += u; }
    if (lane == 63) wred[w] = inc;
    __syncthreads();
    int w0 = wred[0], w1 = wred[1], w2 = wred[2], w3 = wred[3];
    int wofs = (w > 0 ? w0 : 0) + (w > 1 ? w1 : 0) + (w > 2 ? w2 : 0);
    *total = w0 + w1 + w2 + w3;
    __syncthreads();
    return wofs + inc - v;   // exclusive
}

__global__ __launch_bounds__(256) void k_tail(const float* __restrict__ A,
                                              const int* __restrict__ counts,
                                              const int* __restrict__ attn_seed,
                                              float* __restrict__ simrow,
                                              float* __restrict__ subsim,
                                              int* __restrict__ bar,
                                              int* __restrict__ outp) {
    __shared__ float ss[128 * 128];   // 64 KB: av (stage D) / ssT rotated (stage E)
    __shared__ int redA[256], redB[256];
    __shared__ int wred[4];
    __shared__ int act_s[128];
    __shared__ int alive[128];
    __shared__ int lab[128];
    __shared__ unsigned char nbr[128][8];
    __shared__ int ncnt[128];
    __shared__ int chg;
    int tid = threadIdx.x, lane = tid & 63, w = tid >> 6;
    int blk = blockIdx.x;

    // ---- stage A: EVERY block redundantly: argmin(counts) -> blended seed ----
    int seed;
    {
        int bc = 0x7fffffff, bI = 0;
        for (int j = tid; j < NP; j += 256) {
            int c = counts[j];
            if (c < bc) { bc = c; bI = j; }
        }
        redA[tid] = bc; redB[tid] = bI;
        __syncthreads();
        for (int st = 128; st > 0; st >>= 1) {
            if (tid < st) {
                if (redA[tid + st] < redA[tid] ||
                    (redA[tid + st] == redA[tid] && redB[tid + st] < redB[tid])) {
                    redA[tid] = redA[tid + st];
                    redB[tid] = redB[tid + st];
                }
            }
            __syncthreads();
        }
        int flat = redB[0];
        int sr = flat / WD, sc = flat % WD;
        int vr = sr + attn_seed[0];
        int vc = sc + attn_seed[1];
        int rr, rc;
        if ((vr & 1) == 0) rr = vr >> 1;
        else { int m = vr >> 1; rr = (m & 1) ? m + 1 : m; }   // round-half-to-even
        if ((vc & 1) == 0) rc = vc >> 1;
        else { int m = vc >> 1; rc = (m & 1) ? m + 1 : m; }
        seed = rr * WD + rc;
        __syncthreads();
    }

    // ---- stage B: distributed simrow (32 entries/block) + outp zeroing ----
    {
        float sv[12];
#pragma unroll
        for (int kk = 0; kk < 12; ++kk) sv[kk] = A[(size_t)seed * DD + lane + kk * 64];
        int jbase = blk * 32 + w * 8;
        for (int jj = 0; jj < 8; ++jj) {
            int j = jbase + jj;
            float sum = 0.f;
#pragma unroll
            for (int kk = 0; kk < 12; ++kk)
                sum += sv[kk] * A[(size_t)j * DD + lane + kk * 64];
#pragma unroll
            for (int o = 32; o > 0; o >>= 1) sum += __shfl_down(sum, o);
            if (lane == 0) simrow[j] = sum;
        }
        if (tid < 32) outp[blk * 32 + tid] = 0;
    }
    grid_barrier(bar, 0);

    // ---- stage C: EVERY block redundantly: top-K select + compact into LDS ----
    int M;
    {
        int base = tid * 16;
        unsigned key[16];
#pragma unroll
        for (int n = 0; n < 16; ++n) {
            unsigned b = __float_as_uint(simrow[base + n]);
            key[n] = (b & 0x80000000u) ? ~b : (b | 0x80000000u);   // monotone encode
        }
        unsigned prefix = 0;
        for (int bit = 31; bit >= 0; --bit) {
            unsigned cand = prefix | (1u << bit);
            int c = 0;
#pragma unroll
            for (int n = 0; n < 16; ++n) c += (key[n] >= cand) ? 1 : 0;
            int tot = block_sum256(c, lane, w, wred);
            if (tot >= KTOP) prefix = cand;
        }
        unsigned KT = prefix;
        int cgt = 0, ceq = 0;
#pragma unroll
        for (int n = 0; n < 16; ++n) {
            cgt += (key[n] > KT) ? 1 : 0;
            ceq += (key[n] == KT) ? 1 : 0;
        }
        int totgt = block_sum256(cgt, lane, w, wred);
        int slots = KTOP - totgt;
        int dummy;
        int eqrun = block_exscan256(ceq, lane, w, wred, &dummy);
        int flag[16]; int cf = 0;
#pragma unroll
        for (int n = 0; n < 16; ++n) {
            int j = base + n;
            unsigned k = key[n];
            int topk = (k > KT) || (k == KT && eqrun < slots);
            if (k == KT) ++eqrun;
            int f = (topk && (k >= 0x80000000u || j == seed)) ? 1 : 0;
            flag[n] = f; cf += f;
        }
        int off = block_exscan256(cf, lane, w, wred, &M);
#pragma unroll
        for (int n = 0; n < 16; ++n)
            if (flag[n]) act_s[off++] = base + n;
        __syncthreads();
    }

    // ---- stage D: blocks 0..M-1: subsim row blk -> global ----
    if (blk < M) {
        int ip = act_s[blk];
        for (int k = tid; k < DD; k += 256) ss[k] = A[(size_t)ip * DD + k];
        __syncthreads();
        for (int q = w; q < M; q += 4) {
            int iq = act_s[q];
            float sum = 0.f;
#pragma unroll
            for (int kk = 0; kk < 12; ++kk) {
                int k = lane + kk * 64;
                sum += ss[k] * A[(size_t)iq * DD + k];
            }
#pragma unroll
            for (int o = 32; o > 0; o >>= 1) sum += __shfl_down(sum, o);
            if (lane == 0) subsim[blk * 128 + q] = sum;
        }
    }
    grid_barrier(bar, 1);

    // ---- stage E: block 0 only ----
    if (blk != 0) return;

    // load subsim TRANSPOSED + rotated: ssT(q,p) at ss[q*128 + ((p+q)&127)]
    // (conflict-free writes, conflict-free column reads)
    for (int idx = tid; idx < M * 128; idx += 256) {
        int p = idx >> 7, q = idx & 127;
        ss[q * 128 + ((p + q) & 127)] = subsim[idx];
    }
    __syncthreads();

    // expansion scan with incremental sums: S[p] = sum over alive q of sim[p][q]
    if (tid < 64) {
        float S_lo = 0.f, S_hi = 0.f;
        for (int q = 0; q < M; ++q) {
            S_lo += ss[q * 128 + ((lane + q) & 127)];
            S_hi += ss[q * 128 + ((lane + 64 + q) & 127)];
        }
        float al = (lane < M) ? 1.f : 0.f;
        float ah = (lane + 64 < M) ? 1.f : 0.f;
        for (int p = 0; p < M; ++p) {
            float Sp = (p < 64) ? __shfl(S_lo, p) : __shfl(S_hi, p - 64);
            if (!(Sp > 0.f)) {   // node p dies: remove its column from all sums
                S_lo -= ss[p * 128 + ((lane + p) & 127)];
                S_hi -= ss[p * 128 + ((lane + 64 + p) & 127)];
                if (lane == p)      al = 0.f;
                if (lane + 64 == p) ah = 0.f;
            }
        }
        alive[lane]      = (lane < M && al != 0.f) ? 1 : 0;
        alive[lane + 64] = (lane + 64 < M && ah != 0.f) ? 1 : 0;
    }
    __syncthreads();

    // CC: neighbor lists (<=8 per node) + hook/pointer-jump, O(log) iterations
    if (tid < 128) {
        int a = (tid < M) ? alive[tid] : 0;
        int c = 0;
        if (a) {
            int id = act_s[tid];
            int y = id >> 6, x = id & 63;
            for (int q = 0; q < M; ++q) {
                if (q == tid || !alive[q]) continue;
                int qid = act_s[q];
                int dy = (qid >> 6) - y, dx = (qid & 63) - x;
                if (dy >= -1 && dy <= 1 && dx >= -1 && dx <= 1)
                    nbr[tid][c++] = (unsigned char)q;
            }
        }
        ncnt[tid] = c;
        lab[tid] = a ? tid : 32767;
    }
    __syncthreads();
    while (true) {
        if (tid == 0) chg = 0;
        __syncthreads();
        int local = 0;
        if (tid < M && alive[tid]) {
            int m = lab[tid];
            int nc = ncnt[tid];
            for (int k = 0; k < nc; ++k) { int u = lab[nbr[tid][k]]; if (u < m) m = u; }
            { int u = lab[m]; if (u < m) m = u; }   // jump
            { int u = lab[m]; if (u < m) m = u; }   // jump again
            if (m < lab[tid]) { lab[tid] = m; local = 1; }
        }
        if (local) chg = 1;
        __syncthreads();
        if (chg == 0) break;
        __syncthreads();
    }
    if (tid < M && alive[tid]) outp[act_s[tid]] = act_s[lab[tid]] + 1;
}

extern "C" void kernel_launch(void* const* d_in, const int* in_sizes, int n_in,
                              void* d_out, int out_size, void* d_ws, size_t ws_size,
                              hipStream_t stream) {
    const float* A = (const float*)d_in[0];       // out: (4096, 768) fp32
    const int* attn = (const int*)d_in[1];        // attn_seed: (2,) int32
    int* outp = (int*)d_out;                      // labels: (64,64) int32

    char* ws = (char*)d_ws;
    int*            counts = (int*)(ws);                    // 16 KB
    float*          simrow = (float*)(ws + 16384);          // 16 KB
    int*            bar    = (int*)(ws + 33344);            // 16 ints
    float*          subsim = (float*)(ws + 33792);          // 64 KB
    unsigned short* hi     = (unsigned short*)(ws + 1048576);           // 6.29 MB
    unsigned short* lo     = (unsigned short*)(ws + 1048576 + 6291456); // 6.29 MB

    k_split <<<3072, 256, 0, stream>>>(A, hi, lo, counts, bar);
    k_gemm  <<<528,  256, 0, stream>>>(hi, lo, counts);
    k_tail  <<<NBLK, 256, 0, stream>>>(A, counts, attn, simrow, subsim, bar, outp);
}

// Round 9
// 213.850 us; speedup vs baseline: 1.4291x; 1.0273x over previous
//
#include <hip/hip_runtime.h>
#include <cstdint>

#define NP   4096      // patches
#define DD   768       // embed dim
#define HD   64
#define WD   64
#define KTOP 100
#define BIGL 4097      // N+1

typedef short bf16x8 __attribute__((ext_vector_type(8)));
typedef float f32x4  __attribute__((ext_vector_type(4)));

__device__ __forceinline__ void gload_lds16(const void* g, void* l) {
    __builtin_amdgcn_global_load_lds(
        (const __attribute__((address_space(1))) unsigned int*)(uintptr_t)g,
        (__attribute__((address_space(3))) unsigned int*)(unsigned int)(uintptr_t)l,
        16, 0, 0);
}

__device__ __forceinline__ unsigned short f2bf_rne(float x) {
    unsigned b = __float_as_uint(x);
    unsigned r = b + 0x7FFFu + ((b >> 16) & 1u);
    return (unsigned short)(r >> 16);
}
__device__ __forceinline__ float bf2f(unsigned short h) {
    return __uint_as_float(((unsigned)h) << 16);
}

// ---------------- kernel 1: split A into bf16 hi+lo; zero counts ----------------
__global__ __launch_bounds__(256) void k_split(const float* __restrict__ A,
                                               unsigned short* __restrict__ hi,
                                               unsigned short* __restrict__ lo,
                                               int* __restrict__ counts) {
    if (blockIdx.x < 16) counts[blockIdx.x * 256 + threadIdx.x] = 0;
    int idx = blockIdx.x * 256 + threadIdx.x;       // float4 index
    float4 v = ((const float4*)A)[idx];
    unsigned short h0 = f2bf_rne(v.x), h1 = f2bf_rne(v.y),
                   h2 = f2bf_rne(v.z), h3 = f2bf_rne(v.w);
    unsigned short l0 = f2bf_rne(v.x - bf2f(h0)), l1 = f2bf_rne(v.y - bf2f(h1)),
                   l2 = f2bf_rne(v.z - bf2f(h2)), l3 = f2bf_rne(v.w - bf2f(h3));
    ((ushort4*)hi)[idx] = make_ushort4(h0, h1, h2, h3);
    ((ushort4*)lo)[idx] = make_ushort4(l0, l1, l2, l3);
}

// ---------------- kernel 2: split-bf16 MFMA GEMM, 4-tile K=32 groups, dbuf ----------------
__device__ __forceinline__ void stage_group(const unsigned short* __restrict__ hi,
                                            const unsigned short* __restrict__ lo,
                                            int i0, int j0, int kbase, int tid,
                                            unsigned short* G) {
    const unsigned short* srcs[4] = {
        hi + (size_t)i0 * DD + kbase, lo + (size_t)i0 * DD + kbase,
        hi + (size_t)j0 * DD + kbase, lo + (size_t)j0 * DD + kbase };
#pragma unroll
    for (int q = 0; q < 8; ++q) {
        const int tile = q >> 1;
        int pp = (q & 1) * 256 + tid;            // phys chunk 0..511 within tile
        int u = pp >> 2;
        int row = u ^ ((u >> 2) & 1);            // inverse of the bijection
        int kc = (pp & 3) ^ (row & 3);
        gload_lds16(srcs[tile] + (size_t)row * DD + kc * 8,
                    G + (tile * 512 + pp) * 8);
    }
}

__global__ __launch_bounds__(256) void k_gemm(const unsigned short* __restrict__ hi,
                                              const unsigned short* __restrict__ lo,
                                              int* __restrict__ counts) {
    __shared__ __align__(16) unsigned short G[2][4 * 512 * 8];   // 2 x 32 KB
    __shared__ int colc[128];
    __shared__ int rowc[128];

    // XCD-locality supertile remap (XCD = blockIdx%8 round-robin):
    int t = ((blockIdx.x & 7) * 66) + (blockIdx.x >> 3);
    int SI = 0, SJ = 0, rem = t;
    for (;;) {
        int sz = (SI == SJ) ? 36 : 64;
        if (rem < sz) break;
        rem -= sz;
        if (++SJ == 4) { ++SI; SJ = SI; }
    }
    int li, lj;
    if (SI == SJ) {
        int r = 0;
        while (rem >= (8 - r)) { rem -= (8 - r); ++r; }
        li = r; lj = r + rem;
    } else { li = rem >> 3; lj = rem & 7; }
    int bi = SI * 8 + li, bj = SJ * 8 + lj;
    int i0 = bi * 128, j0 = bj * 128;

    int tid = threadIdx.x;
    int lane = tid & 63, w = tid >> 6;
    int wm = w & 1, wn = w >> 1;

    f32x4 acc[4][4];
#pragma unroll
    for (int ti = 0; ti < 4; ++ti)
#pragma unroll
        for (int tj = 0; tj < 4; ++tj) { acc[ti][tj][0] = 0.f; acc[ti][tj][1] = 0.f;
                                         acc[ti][tj][2] = 0.f; acc[ti][tj][3] = 0.f; }

    int kcf = lane >> 4;
    int pa[4], pb[4];
#pragma unroll
    for (int tt = 0; tt < 4; ++tt) {
        int arow = wm * 64 + tt * 16 + (lane & 15);
        pa[tt] = ((arow * 4 + (kcf ^ (arow & 3))) ^ (arow & 4));
        int brow = wn * 64 + tt * 16 + (lane & 15);
        pb[tt] = ((brow * 4 + (kcf ^ (brow & 3))) ^ (brow & 4));
    }

    stage_group(hi, lo, i0, j0, 0, tid, G[0]);   // prologue
    for (int it = 0; it < 24; ++it) {
        int cur = it & 1;
        __syncthreads();
        if (it + 1 < 24)
            stage_group(hi, lo, i0, j0, (it + 1) * 32, tid, G[cur ^ 1]);
        bf16x8 ahi[4], alo[4], bhi[4], blo[4];
#pragma unroll
        for (int tt = 0; tt < 4; ++tt) {
            ahi[tt] = *(const bf16x8*)&G[cur][(0 * 512 + pa[tt]) * 8];
            alo[tt] = *(const bf16x8*)&G[cur][(1 * 512 + pa[tt]) * 8];
            bhi[tt] = *(const bf16x8*)&G[cur][(2 * 512 + pb[tt]) * 8];
            blo[tt] = *(const bf16x8*)&G[cur][(3 * 512 + pb[tt]) * 8];
        }
#pragma unroll
        for (int ti = 0; ti < 4; ++ti)
#pragma unroll
            for (int tj = 0; tj < 4; ++tj) {
                acc[ti][tj] = __builtin_amdgcn_mfma_f32_16x16x32_bf16(
                    ahi[ti], bhi[tj], acc[ti][tj], 0, 0, 0);
                acc[ti][tj] = __builtin_amdgcn_mfma_f32_16x16x32_bf16(
                    alo[ti], bhi[tj], acc[ti][tj], 0, 0, 0);
                acc[ti][tj] = __builtin_amdgcn_mfma_f32_16x16x32_bf16(
                    ahi[ti], blo[tj], acc[ti][tj], 0, 0, 0);
            }
    }

    if (tid < 128) { colc[tid] = 0; rowc[tid] = 0; }
    __syncthreads();

    int nl = lane & 15;
    int rg = lane >> 4;
#pragma unroll
    for (int ti = 0; ti < 4; ++ti)
#pragma unroll
        for (int tj = 0; tj < 4; ++tj) {
            f32x4 a = acc[ti][tj];
            int ct = ((a[0] >= 0.f) ? 1 : 0) + ((a[1] >= 0.f) ? 1 : 0) +
                     ((a[2] >= 0.f) ? 1 : 0) + ((a[3] >= 0.f) ? 1 : 0);
            ct += __shfl_xor(ct, 16);
            ct += __shfl_xor(ct, 32);
            if (rg == 0) atomicAdd(&colc[wn * 64 + tj * 16 + nl], ct);
            if (bi != bj) {
#pragma unroll
                for (int g = 0; g < 4; ++g) {
                    int rv = (a[g] >= 0.f) ? 1 : 0;
                    rv += __shfl_xor(rv, 1);
                    rv += __shfl_xor(rv, 2);
                    rv += __shfl_xor(rv, 4);
                    rv += __shfl_xor(rv, 8);
                    if (nl == 0) atomicAdd(&rowc[wm * 64 + ti * 16 + rg * 4 + g], rv);
                }
            }
        }
    __syncthreads();
    if (tid < 128) {
        atomicAdd(&counts[j0 + tid], colc[tid]);
        if (bi != bj) atomicAdd(&counts[i0 + tid], rowc[tid]);
    }
}

// ---------------- helpers for select ----------------
__device__ __forceinline__ int block_sum256(int v, int lane, int w, int* wred) {
#pragma unroll
    for (int o = 1; o < 64; o <<= 1) v += __shfl_xor(v, o);
    if (lane == 0) wred[w] = v;
    __syncthreads();
    int tt = wred[0] + wred[1] + wred[2] + wred[3];
    __syncthreads();
    return tt;
}
__device__ __forceinline__ int block_exscan256(int v, int lane, int w, int* wred,
                                               int* total) {
    int inc = v;
#pragma unroll
    for (int o = 1; o < 64; o <<= 1) { int u = __shfl_up(inc, o); if (lane >= o) inc += u; }
    if (lane == 63) wred[w] = inc;
    __syncthreads();
    int w0 = wred[0], w1 = wred[1], w2 = wred[2], w3 = wred[3];
    int wofs = (w > 0 ? w0 : 0) + (w > 1 ? w1 : 0) + (w > 2 ? w2 : 0);
    *total = w0 + w1 + w2 + w3;
    __syncthreads();
    return wofs + inc - v;   // exclusive
}

// ---------------- kernel 3: argmin seed (redundant/block) + simrow + zero outp ----------------
__global__ __launch_bounds__(256) void k_seedrow(const float* __restrict__ A,
                                                 const int* __restrict__ counts,
                                                 const int* __restrict__ attn_seed,
                                                 float* __restrict__ simrow,
                                                 int* __restrict__ seedp,
                                                 int* __restrict__ outp) {
    __shared__ int redA[256], redB[256];
    int tid = threadIdx.x, lane = tid & 63, w = tid >> 6;
    int blk = blockIdx.x;

    int bc = 0x7fffffff, bI = 0;
    for (int j = tid; j < NP; j += 256) {
        int c = counts[j];
        if (c < bc) { bc = c; bI = j; }
    }
    redA[tid] = bc; redB[tid] = bI;
    __syncthreads();
    for (int st = 128; st > 0; st >>= 1) {
        if (tid < st) {
            if (redA[tid + st] < redA[tid] ||
                (redA[tid + st] == redA[tid] && redB[tid + st] < redB[tid])) {
                redA[tid] = redA[tid + st];
                redB[tid] = redB[tid + st];
            }
        }
        __syncthreads();
    }
    int flat = redB[0];
    int sr = flat / WD, sc = flat % WD;
    int vr = sr + attn_seed[0];
    int vc = sc + attn_seed[1];
    int rr, rc;
    if ((vr & 1) == 0) rr = vr >> 1;
    else { int m = vr >> 1; rr = (m & 1) ? m + 1 : m; }   // round-half-to-even
    if ((vc & 1) == 0) rc = vc >> 1;
    else { int m = vc >> 1; rc = (m & 1) ? m + 1 : m; }
    int seed = rr * WD + rc;
    if (blk == 0 && tid == 0) seedp[0] = seed;

    float sv[12];
#pragma unroll
    for (int kk = 0; kk < 12; ++kk) sv[kk] = A[(size_t)seed * DD + lane + kk * 64];
    int jbase = blk * 32 + w * 8;
    for (int jj = 0; jj < 8; ++jj) {
        int j = jbase + jj;
        float sum = 0.f;
#pragma unroll
        for (int kk = 0; kk < 12; ++kk)
            sum += sv[kk] * A[(size_t)j * DD + lane + kk * 64];
#pragma unroll
        for (int o = 32; o > 0; o >>= 1) sum += __shfl_down(sum, o);
        if (lane == 0) simrow[j] = sum;
    }
    if (tid < 32) outp[blk * 32 + tid] = 0;
}

// ---------------- kernel 4: top-K select + compact (1 block) ----------------
__global__ __launch_bounds__(256) void k_sel(const float* __restrict__ simrow,
                                             const int* __restrict__ seedp,
                                             int* __restrict__ act, int* __restrict__ Mp) {
    __shared__ int wred[4];
    int tid = threadIdx.x, lane = tid & 63, w = tid >> 6;
    int seed = seedp[0];
    int base = tid * 16;
    unsigned key[16];
#pragma unroll
    for (int n = 0; n < 16; ++n) {
        unsigned b = __float_as_uint(simrow[base + n]);
        key[n] = (b & 0x80000000u) ? ~b : (b | 0x80000000u);   // monotone encode
    }
    unsigned prefix = 0;
    for (int bit = 31; bit >= 0; --bit) {
        unsigned cand = prefix | (1u << bit);
        int c = 0;
#pragma unroll
        for (int n = 0; n < 16; ++n) c += (key[n] >= cand) ? 1 : 0;
        int tot = block_sum256(c, lane, w, wred);
        if (tot >= KTOP) prefix = cand;
    }
    unsigned KT = prefix;
    int cgt = 0, ceq = 0;
#pragma unroll
    for (int n = 0; n < 16; ++n) {
        cgt += (key[n] > KT) ? 1 : 0;
        ceq += (key[n] == KT) ? 1 : 0;
    }
    int totgt = block_sum256(cgt, lane, w, wred);
    int slots = KTOP - totgt;
    int dummy;
    int eqrun = block_exscan256(ceq, lane, w, wred, &dummy);
    int flag[16]; int cf = 0;
#pragma unroll
    for (int n = 0; n < 16; ++n) {
        int j = base + n;
        unsigned k = key[n];
        int topk = (k > KT) || (k == KT && eqrun < slots);
        if (k == KT) ++eqrun;
        int f = (topk && (k >= 0x80000000u || j == seed)) ? 1 : 0;
        flag[n] = f; cf += f;
    }
    int M;
    int off = block_exscan256(cf, lane, w, wred, &M);
    if (tid == 0) Mp[0] = M;
#pragma unroll
    for (int n = 0; n < 16; ++n)
        if (flag[n]) act[off++] = base + n;
}

// ---------------- kernel 5: subsim rows ----------------
__global__ __launch_bounds__(256) void k_sub(const float* __restrict__ A,
                                             const int* __restrict__ act,
                                             const int* __restrict__ Mp,
                                             float* __restrict__ subsim) {
    __shared__ float av[DD];
    int M = Mp[0];
    int p = blockIdx.x;
    if (p >= M) return;
    int tid = threadIdx.x, lane = tid & 63, w = tid >> 6;
    int ip = act[p];
    for (int k = tid; k < DD; k += 256) av[k] = A[(size_t)ip * DD + k];
    __syncthreads();
    for (int q = w; q < M; q += 4) {
        int iq = act[q];
        float sum = 0.f;
#pragma unroll
        for (int kk = 0; kk < 12; ++kk) {
            int k = lane + kk * 64;
            sum += av[k] * A[(size_t)iq * DD + k];
        }
#pragma unroll
        for (int o = 32; o > 0; o >>= 1) sum += __shfl_down(sum, o);
        if (lane == 0) subsim[p * 128 + q] = sum;
    }
}

// ---------------- kernel 6: expansion scan + CC (1 block) ----------------
__global__ __launch_bounds__(256) void k_fin(const float* __restrict__ subsim,
                                             const int* __restrict__ act,
                                             const int* __restrict__ Mp,
                                             int* __restrict__ outp) {
    __shared__ float ss[128 * 128];   // 64 KB, transposed+rotated
    __shared__ int act_s[128];
    __shared__ int alive[128];
    __shared__ int lab[128];
    __shared__ unsigned char nbr[128][8];
    __shared__ int ncnt[128];
    __shared__ int chg;
    int M = Mp[0];
    int tid = threadIdx.x, lane = tid & 63;

    if (tid < 128) act_s[tid] = (tid < M) ? act[tid] : 0;
    // ssT(q,p) at ss[q*128 + ((p+q)&127)]: conflict-free writes & column reads
    for (int idx = tid; idx < M * 128; idx += 256) {
        int p = idx >> 7, q = idx & 127;
        ss[q * 128 + ((p + q) & 127)] = subsim[idx];
    }
    __syncthreads();

    // expansion scan with incremental sums
    if (tid < 64) {
        float S_lo = 0.f, S_hi = 0.f;
        for (int q = 0; q < M; ++q) {
            S_lo += ss[q * 128 + ((lane + q) & 127)];
            S_hi += ss[q * 128 + ((lane + 64 + q) & 127)];
        }
        float al = (lane < M) ? 1.f : 0.f;
        float ah = (lane + 64 < M) ? 1.f : 0.f;
        for (int p = 0; p < M; ++p) {
            float Sp = (p < 64) ? __shfl(S_lo, p) : __shfl(S_hi, p - 64);
            if (!(Sp > 0.f)) {   // node p dies: remove its column from all sums
                S_lo -= ss[p * 128 + ((lane + p) & 127)];
                S_hi -= ss[p * 128 + ((lane + 64 + p) & 127)];
                if (lane == p)      al = 0.f;
                if (lane + 64 == p) ah = 0.f;
            }
        }
        alive[lane]      = (lane < M && al != 0.f) ? 1 : 0;
        alive[lane + 64] = (lane + 64 < M && ah != 0.f) ? 1 : 0;
    }
    __syncthreads();

    // CC: neighbor lists + hook/pointer-jump
    if (tid < 128) {
        int a = (tid < M) ? alive[tid] : 0;
        int c = 0;
        if (a) {
            int id = act_s[tid];
            int y = id >> 6, x = id & 63;
            for (int q = 0; q < M; ++q) {
                if (q == tid || !alive[q]) continue;
                int qid = act_s[q];
                int dy = (qid >> 6) - y, dx = (qid & 63) - x;
                if (dy >= -1 && dy <= 1 && dx >= -1 && dx <= 1)
                    nbr[tid][c++] = (unsigned char)q;
            }
        }
        ncnt[tid] = c;
        lab[tid] = a ? tid : 32767;
    }
    __syncthreads();
    while (true) {
        if (tid == 0) chg = 0;
        __syncthreads();
        int local = 0;
        if (tid < M && alive[tid]) {
            int m = lab[tid];
            int nc = ncnt[tid];
            for (int k = 0; k < nc; ++k) { int u = lab[nbr[tid][k]]; if (u < m) m = u; }
            { int u = lab[m]; if (u < m) m = u; }   // jump
            { int u = lab[m]; if (u < m) m = u; }   // jump again
            if (m < lab[tid]) { lab[tid] = m; local = 1; }
        }
        if (local) chg = 1;
        __syncthreads();
        if (chg == 0) break;
        __syncthreads();
    }
    if (tid < M && alive[tid]) outp[act_s[tid]] = act_s[lab[tid]] + 1;
}

extern "C" void kernel_launch(void* const* d_in, const int* in_sizes, int n_in,
                              void* d_out, int out_size, void* d_ws, size_t ws_size,
                              hipStream_t stream) {
    const float* A = (const float*)d_in[0];       // out: (4096, 768) fp32
    const int* attn = (const int*)d_in[1];        // attn_seed: (2,) int32
    int* outp = (int*)d_out;                      // labels: (64,64) int32

    char* ws = (char*)d_ws;
    int*            counts = (int*)(ws);                    // 16 KB
    float*          simrow = (float*)(ws + 16384);          // 16 KB
    int*            act    = (int*)(ws + 32768);            // 512 B
    int*            Mp     = (int*)(ws + 33280);
    int*            seedp  = (int*)(ws + 33284);
    float*          subsim = (float*)(ws + 33792);          // 64 KB
    unsigned short* hi     = (unsigned short*)(ws + 1048576);           // 6.29 MB
    unsigned short* lo     = (unsigned short*)(ws + 1048576 + 6291456); // 6.29 MB

    k_split  <<<3072, 256, 0, stream>>>(A, hi, lo, counts);
    k_gemm   <<<528,  256, 0, stream>>>(hi, lo, counts);
    k_seedrow<<<128,  256, 0, stream>>>(A, counts, attn, simrow, seedp, outp);
    k_sel    <<<1,    256, 0, stream>>>(simrow, seedp, act, Mp);
    k_sub    <<<128,  256, 0, stream>>>(A, act, Mp, subsim);
    k_fin    <<<1,    256, 0, stream>>>(subsim, act, Mp, outp);
}